// Round 7
// baseline (140.136 us; speedup 1.0000x reference)
//
#include <hip/hip_runtime.h>

// KAN layer as one fused fp16 MFMA GEMM:
//   out[b,i] = sum_j [ neg*bw*pw + pos*bw + sum_k basis[b,j,k]*sw[i,j]*sc[i,j,k] ]
// A  [2048 x 11264] fp16 : per j, 22 slots = {20 basis (5 nonzero), neg, pos}
// Ct [ 512 x 11264] fp16 : per j, 22 slots = {sw*sc[0..19], bw*pw, bw}   (B^T layout)
// R10: gemm256 — halve per-FLOP LDS traffic at PROVEN BK=32 geometry.
//   R9b decoded the logjam: prep ~40, gemm ~40, both stuck. Model (matches
//   R5/R6/R7/R8): gemm is ~88% LDS-pipe-bound (per chunk/CU: 32 ds_read_b128
//   x2 blocks ~= 1024 cy vs 1165 measured). Fix: block 256x256, 512 thr,
//   8 waves (2m x 4n), wave-tile 128x64 -> 12 ds_read/wave/chunk for 4x the
//   FLOPs of R6's block (24 KB LDS-read per R6-FLOP-equiv vs 48). Rows stay
//   64 B so R6's measured-zero-conflict swizzle + staging pattern copy
//   VERBATIM (R8's BK=64 swizzle was wrong -> ~8-way conflicts, regressed).
//   KSPLIT=16 (22 chunks), 2 z/XCD pin, reduce16 (+5 us, known). Predicted
//   gemm ~15-18 us (MFMA roofline 12 us; LDS 1412 vs MFMA 1241 cy/chunk).
// R9b: prep2 register-built (== prep_all ~40 us; fusion target next round).
// R5: non-atomic partials; 3-deep pipeline, counted vmcnt, setprio on MFMA.
// ws usage: A = 46.1 MB, Ct = 11.5 MB, partials16 = 67.1 MB (124.9 MB total).

typedef _Float16 half_t;
typedef __attribute__((ext_vector_type(8))) _Float16 half8;
typedef __attribute__((ext_vector_type(4))) float floatx4;

#define B_DIM   2048
#define J_DIM   512
#define O_DIM   512
#define SLOTS   22
#define K_TOT   (J_DIM * SLOTS)      // 11264
#define BM      256
#define BN      256
#define BK      32
#define KSPLIT  16                   // 2 z per XCD

// ---------------------------------------------------------------------------
// Quartic B-spline local basis, uniform knots g_i = -1.5 + i*(3.125/24).
// (Reference quirk: linspace(-1.5, 1.625, 25) -> spacing 3.125/24, NOT 0.125.)
// m in [3,19]; window k = m-4 .. m, entries with k<0 dropped.
__device__ __forceinline__ void bspline5(float xc, int& k0, float Nv[5]) {
    const float invS = 7.68f;              // 24/3.125 (exact ratio)
    float u = (xc + 1.5f) * invS;          // knot units
    int m = (int)u;
    m = min(max(m, 3), 19);
    k0 = m - 4;
    Nv[0] = 1.f; Nv[1] = 0.f; Nv[2] = 0.f; Nv[3] = 0.f; Nv[4] = 0.f;
#pragma unroll
    for (int d = 1; d <= 4; ++d) {
        float nw[5];
        float inv_d = 1.0f / (float)d;
#pragma unroll
        for (int r = 0; r < 5; ++r) {
            if (r > d) { nw[r] = 0.f; continue; }
            float kk = (float)(m - d + r);
            float acc = 0.f;
            if (r >= 1) acc += (u - kk) * Nv[r - 1];
            if (r < d)  acc += (kk + (float)(d + 1) - u) * Nv[r];
            nw[r] = acc * inv_d;
        }
#pragma unroll
        for (int r = 0; r < 5; ++r) Nv[r] = nw[r];
    }
}

__device__ __forceinline__ unsigned packh2(float a, float b) {
    half_t ha = (half_t)a, hb = (half_t)b;    // RTN, identical to old path
    unsigned short ua = __builtin_bit_cast(unsigned short, ha);
    unsigned short ub = __builtin_bit_cast(unsigned short, hb);
    return (unsigned)ua | ((unsigned)ub << 16);
}

// ---------------------------------------------------------------------------
// prep2: blocks [0,256) build Ct (2 i-rows each, register-only);
//        blocks [256,1280) build A (2 b-rows each, private-LDS scatter).
// Thread: sub = t>>7 selects the row within the block; jq = t&127 -> j0=4*jq.
__global__ __launch_bounds__(256) void prep2(const float* __restrict__ x,
                                             const float* __restrict__ pw,
                                             const float* __restrict__ bw,
                                             const float* __restrict__ sw,
                                             const float* __restrict__ sc,
                                             half_t* __restrict__ A,
                                             half_t* __restrict__ Ct) {
    __shared__ half_t sbuf[2][128 * 88];   // 45056 B, prep_A path only
    int bid = blockIdx.x;
    int t = threadIdx.x;
    int sub = t >> 7;          // 0/1: which row of the block's pair
    int jq  = t & 127;         // j-quad index
    int j0  = jq * 4;

    if (bid < 256) {
        // ---- prep_C: 4 records built fully in registers, no LDS.
        int i = bid * 2 + sub;
        size_t ij0 = (size_t)i * J_DIM + j0;
        float4 s4 = *(const float4*)(sw + ij0);
        float4 b4 = *(const float4*)(bw + ij0);
        float4 p4 = *(const float4*)(pw + ij0);
        const float4* sp4 = (const float4*)(sc + ij0 * 20);  // 20 float4s
        unsigned u[44];
#pragma unroll
        for (int jj = 0; jj < 4; ++jj) {
            float s = ((const float*)&s4)[jj];
            float b = ((const float*)&b4)[jj];
            float p = ((const float*)&p4)[jj];
#pragma unroll
            for (int v = 0; v < 5; ++v) {                   // 20 coeffs
                float4 c4 = sp4[jj * 5 + v];
                u[jj * 11 + v * 2 + 0] = packh2(s * c4.x, s * c4.y);
                u[jj * 11 + v * 2 + 1] = packh2(s * c4.z, s * c4.w);
            }
            u[jj * 11 + 10] = packh2(b * p, b);             // slots 20,21
        }
        uint4* dst = (uint4*)(Ct + (size_t)i * K_TOT + (size_t)j0 * SLOTS);
#pragma unroll
        for (int v = 0; v < 11; ++v)
            dst[v] = make_uint4(u[4 * v], u[4 * v + 1], u[4 * v + 2], u[4 * v + 3]);
        return;
    }

    // ---- prep_A: 4 records via private-LDS scatter (no cross-thread deps
    // until the single pre-copy barrier).
    int b0 = (bid - 256) * 2;
    int b = b0 + sub;
    float4 x4 = *(const float4*)(x + (size_t)b * J_DIM + j0);
    half_t* reg = &sbuf[sub][jq * 88];      // 176 B, 16B-aligned, stride 11 quads

    // zero 88 halfs with 11 conflict-free b128 writes (stride 176 B = 11 quads)
    half8 z;
#pragma unroll
    for (int e = 0; e < 8; ++e) z[e] = (half_t)0.f;
#pragma unroll
    for (int v = 0; v < 11; ++v) *(half8*)(reg + v * 8) = z;

#pragma unroll
    for (int jj = 0; jj < 4; ++jj) {
        float xv = ((const float*)&x4)[jj];
        float xc = fminf(fmaxf(xv, -1.f), 1.f);
        float pos = fmaxf(xc, 0.f);
        float neg = xc - pos;
        int k0; float Nv[5];
        bspline5(xc, k0, Nv);
        half_t* rb = reg + jj * SLOTS;
#pragma unroll
        for (int rr = 0; rr < 5; ++rr) {
            int k = k0 + rr;
            if (k >= 0) rb[k] = (half_t)Nv[rr];   // k <= 19 guaranteed
        }
        *(unsigned*)(rb + 20) = packh2(neg, pos); // 4B-aligned (44*jj+40)
    }
    __syncthreads();

    // coalesced cooperative store of the 2 complete rows (45056 B)
    const uint4* src = (const uint4*)&sbuf[0][0];
    uint4* dst = (uint4*)(A + (size_t)b0 * K_TOT);
#pragma unroll
    for (int v = 0; v < 11; ++v) dst[v * 256 + t] = src[v * 256 + t];
}

// ---------------------------------------------------------------------------
// gemm256: grid (8,2,16) = 256 blocks (1/CU), 512 thr = 8 waves (2m x 4n),
// wave-tile 128x64, acc[8][4]. BK=32 (64 B rows — R6's zero-conflict swizzle
// verbatim). 3-deep LDS pipeline: loads 2 chunks ahead, loop-top vmcnt(4)
// (chunk c's 4 per-wave loads done, c+1's flying), raw s_barrier, setprio(1)
// around the 32-MFMA cluster. vmcnt drains to 0 only at the last chunk.
// XCD pin: XCD c owns bz in {c, c+8} (A-slice 2.88x2 + Ct-slice 0.72x2 MB).
__global__ __launch_bounds__(512, 2) void gemm256_f16(const half_t* __restrict__ A,
                                                      const half_t* __restrict__ Bt,
                                                      float* __restrict__ out) {
    constexpr int KS_LEN = K_TOT / KSPLIT;     // 704
    constexpr int KCH = KS_LEN / BK;           // 22

    __shared__ half_t As[3][BM * BK];   // 3 x 16 KB
    __shared__ half_t Bs[3][BN * BK];   // 3 x 16 KB   (96 KB total)

    // dispatch order x-fastest: lid = x + 8*(y + 2*z); XCD = lid % 8.
    int lid = blockIdx.x + 8 * (blockIdx.y + 2 * blockIdx.z);   // 0..255
    int c8 = lid & 7;                // XCD
    int r2 = lid >> 3;               // 0..31
    int bz = c8 + 8 * (r2 & 1);      // z in {c8, c8+8}
    int rr2 = r2 >> 1;               // 0..15
    int bx = rr2 & 7;                // 8 m-blocks
    int by = rr2 >> 3;               // 2 n-blocks

    int m0 = bx * BM;
    int n0 = by * BN;
    int ks = bz * KS_LEN;            // halfs; 16B-aligned

    int t = threadIdx.x;
    int w = t >> 6;                  // wave 0..7
    int l = t & 63;
    int wm = w >> 2, wn = w & 3;     // wave grid 2 x 4

    floatx4 acc[8][4] = {};

    int lrow = l >> 2;                            // 0..15: row within 16-row group
    int lkof = (((l & 3) ^ ((l >> 3) & 3)) * 8);  // swizzled k-quad source offset (R6)

    const half_t* gA = A + (size_t)m0 * K_TOT + ks;
    const half_t* gB = Bt + (size_t)n0 * K_TOT + ks;

    int q = l >> 4;               // 0..3
    int fr = l & 15;              // 0..15
    int qs = (q ^ ((fr >> 1) & 3)) * 8;  // swizzled read offset (R6, conflicts=0)

// 4 global_load_lds per thread per chunk (2 A + 2 B) -> vmcnt counts in 4s.
// 8 waves x 2 groups = 16 groups of 16 rows = 256 rows for A; same for B.
#define ISSUE_LOADS(c, p)                                                     \
    {                                                                         \
        int kb = (c) * BK;                                                    \
        _Pragma("unroll")                                                     \
        for (int s = 0; s < 2; ++s) {                                         \
            int r = (w * 2 + s) * 16 + lrow;                                  \
            __builtin_amdgcn_global_load_lds(                                 \
                (const __attribute__((address_space(1))) unsigned int*)       \
                    (gA + (size_t)r * K_TOT + kb + lkof),                     \
                (__attribute__((address_space(3))) unsigned int*)             \
                    (&As[p][0] + (w * 2 + s) * 512),                          \
                16, 0, 0);                                                    \
            __builtin_amdgcn_global_load_lds(                                 \
                (const __attribute__((address_space(1))) unsigned int*)       \
                    (gB + (size_t)r * K_TOT + kb + lkof),                     \
                (__attribute__((address_space(3))) unsigned int*)             \
                    (&Bs[p][0] + (w * 2 + s) * 512),                          \
                16, 0, 0);                                                    \
        }                                                                     \
    }

    ISSUE_LOADS(0, 0)
    ISSUE_LOADS(1, 1)

    int pb = 0;                              // consume buffer = c % 3
    for (int c = 0; c < KCH; ++c) {
        if (c + 2 < KCH) {
            asm volatile("s_waitcnt vmcnt(4)" ::: "memory");
            __builtin_amdgcn_s_barrier();
            int pn = pb + 2; if (pn >= 3) pn -= 3;
            ISSUE_LOADS(c + 2, pn)
        } else if (c + 2 == KCH) {
            asm volatile("s_waitcnt vmcnt(4)" ::: "memory");
            __builtin_amdgcn_s_barrier();
        } else {
            asm volatile("s_waitcnt vmcnt(0)" ::: "memory");
            __builtin_amdgcn_s_barrier();
        }

        // 12 ds_read_b128 per wave per chunk: 8 af + 4 bf
        half8 af[8], bf[4];
#pragma unroll
        for (int nt = 0; nt < 4; ++nt)
            bf[nt] = *(const half8*)(&Bs[pb][0] + (wn * 64 + nt * 16 + fr) * BK + qs);
#pragma unroll
        for (int mt = 0; mt < 8; ++mt)
            af[mt] = *(const half8*)(&As[pb][0] + (wm * 128 + mt * 16 + fr) * BK + qs);

        __builtin_amdgcn_s_setprio(1);
#pragma unroll
        for (int mt = 0; mt < 8; ++mt)
#pragma unroll
            for (int nt = 0; nt < 4; ++nt)
                acc[mt][nt] = __builtin_amdgcn_mfma_f32_16x16x32_f16(
                    af[mt], bf[nt], acc[mt][nt], 0, 0, 0);
        __builtin_amdgcn_s_setprio(0);

        if (++pb == 3) pb = 0;
    }
#undef ISSUE_LOADS

    // epilogue: C/D layout col = lane&15, row = (lane>>4)*4 + reg (m89-verified)
    float* dst = out + (size_t)bz * ((size_t)B_DIM * O_DIM);
#pragma unroll
    for (int mt = 0; mt < 8; ++mt)
#pragma unroll
        for (int nt = 0; nt < 4; ++nt) {
            int rw = m0 + wm * 128 + mt * 16 + q * 4;
            int cc = n0 + wn * 64 + nt * 16 + fr;
#pragma unroll
            for (int rg = 0; rg < 4; ++rg)
                dst[(size_t)(rw + rg) * O_DIM + cc] = acc[mt][nt][rg];
        }
}

// ---------------------------------------------------------------------------
// Sum the KSPLIT partial buffers into out. 71 MB traffic, BW-bound (~11 us).
__global__ __launch_bounds__(256) void reduce16(const float* __restrict__ parts,
                                                float* __restrict__ out) {
    constexpr int N4 = B_DIM * O_DIM / 4;
    int i = blockIdx.x * 256 + threadIdx.x;       // float4 index
    const float4* p = (const float4*)parts;
    float4 a = p[i];
#pragma unroll
    for (int z = 1; z < KSPLIT; ++z) {
        float4 b = p[(size_t)z * N4 + i];
        a.x += b.x; a.y += b.y; a.z += b.z; a.w += b.w;
    }
    ((float4*)out)[i] = a;
}

// ---------------------------------------------------------------------------
// Zero-workspace fallback (only if ws_size too small): correct but slow.
__global__ __launch_bounds__(256) void kan_fallback(const float* __restrict__ x,
                                                    const float* __restrict__ pw,
                                                    const float* __restrict__ bw,
                                                    const float* __restrict__ sw,
                                                    const float* __restrict__ sc,
                                                    float* __restrict__ out) {
    __shared__ float s_neg[J_DIM], s_pos[J_DIM], s_bas[J_DIM][5];
    __shared__ int s_k0[J_DIM];
    int b = blockIdx.x;
    int t = threadIdx.x;
#pragma unroll
    for (int jj = 0; jj < 2; ++jj) {
        int j = t + jj * 256;
        float xv = x[(size_t)b * J_DIM + j];
        float xc = fminf(fmaxf(xv, -1.f), 1.f);
        float pos = fmaxf(xc, 0.f);
        s_pos[j] = pos;
        s_neg[j] = xc - pos;
        int k0; float Nv[5];
        bspline5(xc, k0, Nv);
        s_k0[j] = k0;
#pragma unroll
        for (int r = 0; r < 5; ++r) s_bas[j][r] = Nv[r];
    }
    __syncthreads();
    for (int i = t; i < O_DIM; i += 256) {
        float acc = 0.f;
        for (int j = 0; j < J_DIM; ++j) {
            size_t ij = (size_t)i * J_DIM + j;
            float bwv = bw[ij];
            acc += bwv * (pw[ij] * s_neg[j] + s_pos[j]);
            int k0 = s_k0[j];
            const float* cp = sc + ij * 20;
            float sp = 0.f;
#pragma unroll
            for (int r = 0; r < 5; ++r) {
                int k = k0 + r;
                if (k >= 0) sp += s_bas[j][r] * cp[k];
            }
            acc += sw[ij] * sp;
        }
        out[(size_t)b * O_DIM + i] = acc;
    }
}

// ---------------------------------------------------------------------------
extern "C" void kernel_launch(void* const* d_in, const int* in_sizes, int n_in,
                              void* d_out, int out_size, void* d_ws, size_t ws_size,
                              hipStream_t stream) {
    const float* x  = (const float*)d_in[0];
    const float* pw = (const float*)d_in[1];
    const float* bw = (const float*)d_in[2];
    const float* sw = (const float*)d_in[3];
    const float* sc = (const float*)d_in[4];
    float* out = (float*)d_out;

    const size_t abct = (size_t)(B_DIM + O_DIM) * K_TOT * sizeof(half_t);       // 57.7 MB
    const size_t parts_bytes = (size_t)KSPLIT * B_DIM * O_DIM * sizeof(float);  // 67.1 MB

    if (ws_size >= abct + parts_bytes) {
        half_t* A  = (half_t*)d_ws;
        half_t* Ct = A + (size_t)B_DIM * K_TOT;
        float* parts = (float*)((char*)d_ws + abct);   // 16B-aligned (abct % 16 == 0)

        prep2<<<256 + B_DIM / 2, 256, 0, stream>>>(x, pw, bw, sw, sc, A, Ct);
        dim3 g(B_DIM / BM, O_DIM / BN, KSPLIT);        // (8, 2, 16)
        gemm256_f16<<<g, 512, 0, stream>>>(A, Ct, parts);
        reduce16<<<(B_DIM * O_DIM / 4) / 256, 256, 0, stream>>>(parts, out);
    } else {
        kan_fallback<<<B_DIM, 256, 0, stream>>>(x, pw, bw, sw, sc, out);
    }
}